// Round 1
// baseline (468.485 us; speedup 1.0000x reference)
//
#include <hip/hip_runtime.h>

// LDW lifting-wavelet 2x2 downsample, fused single pass.
// x: [16,64,257,257] f32 -> out: [16,256,128,128] f32
// Bands along channel: [ll(0:64), hl(64:128), lh(128:192), hh(192:256)].

#define B_ 16
#define C_ 64
#define H_ 257
#define W_ 257
#define HO_ 128
#define WO_ 128
#define SEGS 4
#define SEG_ROWS (HO_ / SEGS)   // 32

__global__ __launch_bounds__(256) void ldw_down_kernel(
    const float* __restrict__ x,
    const float* __restrict__ low_h,
    const float* __restrict__ high_h,
    const float* __restrict__ low_v,
    const float* __restrict__ high_v,
    float* __restrict__ out)
{
    const float lh0 = low_h[0],  lh1 = low_h[1];
    const float hh0 = high_h[0], hh1 = high_h[1];
    const float lv0 = low_v[0],  lv1 = low_v[1];
    const float hv0 = high_v[0], hv1 = high_v[1];

    const int tid = blockIdx.x * blockDim.x + threadIdx.x;
    // layout: wo fastest (128) -> lanes coalesced, then seg (4), then plane (1024)
    const int wo  = tid & (WO_ - 1);
    const int seg = (tid >> 7) & (SEGS - 1);
    const int p   = tid >> 9;                 // plane 0..1023
    if (p >= B_ * C_) return;

    const long PLANE_IN = (long)H_ * W_;      // 66049
    const float* xin = x + (long)p * PLANE_IN;

    const int b = p >> 6;                     // /C_
    const int c = p & (C_ - 1);
    const long PLANE_OUT = (long)HO_ * WO_;   // 16384
    // out index: b*(4C*16384) + (band*C + c)*16384 + ho*128 + wo
    float* oll = out + (long)b * (4 * C_) * PLANE_OUT + (long)c * PLANE_OUT + wo;
    float* ohl = oll + (long)C_ * PLANE_OUT;
    float* olh = oll + (long)(2 * C_) * PLANE_OUT;
    float* ohh = oll + (long)(3 * C_) * PLANE_OUT;

    const int ho0 = seg * SEG_ROWS;
    const int col = 2 * wo;                   // cols col, col+1, col+2 (max 256, valid)

    // prime the carried (lifted) top row r = 2*ho0
    {
        const float* r0 = xin + (long)(2 * ho0) * W_ + col;
        float a0 = r0[0], a1 = r0[1], a2 = r0[2];
        // xl0/xh0 carried across iterations
        float xl0 = lh0 * a0 + lh1 * a1;
        float xh0 = hh0 * a1 + hh1 * a2;

        #pragma unroll 4
        for (int i = 0; i < SEG_ROWS; ++i) {
            const int ho = ho0 + i;
            const float* r1 = xin + (long)(2 * ho + 1) * W_ + col;
            const float* r2 = r1 + W_;
            const float b0 = r1[0], b1 = r1[1], b2 = r1[2];
            const float c0 = r2[0], c1 = r2[1], c2 = r2[2];

            const float xl1 = lh0 * b0 + lh1 * b1;
            const float xh1 = hh0 * b1 + hh1 * b2;
            const float xl2 = lh0 * c0 + lh1 * c1;
            const float xh2 = hh0 * c1 + hh1 * c2;

            const long o = (long)ho * WO_;
            oll[o] = lv0 * xl0 + lv1 * xl1;
            ohl[o] = hv0 * xl1 + hv1 * xl2;
            olh[o] = lv0 * xh0 + lv1 * xh1;
            ohh[o] = hv0 * xh1 + hv1 * xh2;

            xl0 = xl2;
            xh0 = xh2;
        }
    }
}

extern "C" void kernel_launch(void* const* d_in, const int* in_sizes, int n_in,
                              void* d_out, int out_size, void* d_ws, size_t ws_size,
                              hipStream_t stream) {
    const float* x      = (const float*)d_in[0];
    const float* low_h  = (const float*)d_in[1];
    const float* high_h = (const float*)d_in[2];
    const float* low_v  = (const float*)d_in[3];
    const float* high_v = (const float*)d_in[4];
    float* out = (float*)d_out;

    const int total_threads = B_ * C_ * WO_ * SEGS;   // 524288
    const int block = 256;
    const int grid = (total_threads + block - 1) / block;  // 2048
    ldw_down_kernel<<<grid, block, 0, stream>>>(x, low_h, high_h, low_v, high_v, out);
}